// Round 1
// baseline (1641.299 us; speedup 1.0000x reference)
//
#include <hip/hip_runtime.h>
#include <cstddef>
#include <cmath>

// Problem constants
#define B_    64
#define L_    128
#define V_    20000
#define D_    300
#define H_    256
#define NE_   34
#define NA_   36
#define M_    8192      // L_*B_
#define KP_   304       // D_ padded to multiple of 16
#define NPROJ_ 2048     // 2 dirs * 4H
#define K2_   512       // 2H
#define NCAT_ 128       // 36 (part_j) + 36 (part_i) + 34 (logit_h) padded to 128

__device__ __forceinline__ float sigmoidf_(float x) { return 1.0f / (1.0f + expf(-x)); }

// ---------------------------------------------------------------------------
// K1: gather embeddings into X (M_ x KP_), zero-padded K tail.
// X[m][k], m = l*B_ + b
__global__ __launch_bounds__(256) void k_gather(const float* __restrict__ emb,
                                                const int* __restrict__ ids,
                                                float* __restrict__ X) {
    int idx = blockIdx.x * 256 + threadIdx.x;           // over M_*KP_
    if (idx >= M_ * KP_) return;
    int m = idx / KP_, k = idx - m * KP_;
    int l = m >> 6, b = m & 63;
    float v = 0.f;
    if (k < D_) {
        int tok = ids[b * L_ + l];
        v = emb[(size_t)tok * D_ + k];
    }
    X[idx] = v;
}

// K2: build transposed input-proj weights Wt_ih (KP_ x NPROJ_) and combined bias
__global__ __launch_bounds__(256) void k_prep_wih(const float* __restrict__ Wf,
                                                  const float* __restrict__ Wb,
                                                  const float* __restrict__ bihf,
                                                  const float* __restrict__ bhhf,
                                                  const float* __restrict__ bihb,
                                                  const float* __restrict__ bhhb,
                                                  float* __restrict__ Wt,
                                                  float* __restrict__ bias) {
    int idx = blockIdx.x * 256 + threadIdx.x;           // over KP_*NPROJ_
    if (idx >= KP_ * NPROJ_) return;
    int k = idx / NPROJ_, n = idx - k * NPROJ_;
    int dir = n >> 10, g = n & 1023;
    float v = 0.f;
    if (k < D_) v = dir ? Wb[g * D_ + k] : Wf[g * D_ + k];
    Wt[idx] = v;
    if (k == 0) bias[n] = dir ? (bihb[g] + bhhb[g]) : (bihf[g] + bhhf[g]);
}

// K3: transpose W_hh to k-major: Wt[dir][k][g]
__global__ __launch_bounds__(256) void k_prep_whh(const float* __restrict__ Wf,
                                                  const float* __restrict__ Wb,
                                                  float* __restrict__ Wt) {
    int idx = blockIdx.x * 256 + threadIdx.x;           // over 2*256*1024
    if (idx >= 2 * H_ * 4 * H_) return;
    int dir = idx >> 18;
    int r = idx & 262143;
    int k = r >> 10, g = r & 1023;
    const float* W = dir ? Wb : Wf;
    Wt[idx] = W[g * H_ + k];
}

// K4: build combined head weights Wcat (K2_ x NCAT_):
//   cols 0..35  : Wj^T  (W_arg[:, :512])
//   cols 36..71 : Wi^T  (W_arg[:, 512:1024]), bias = b_arg
//   cols 72..105: W_ev[:, :512]^T, bias = b_ev
//   cols 106..127: zero
__global__ __launch_bounds__(256) void k_prep_wcat(const float* __restrict__ Warg,
                                                   const float* __restrict__ Wev,
                                                   const float* __restrict__ barg,
                                                   const float* __restrict__ bev,
                                                   float* __restrict__ Wcat,
                                                   float* __restrict__ bias) {
    int idx = blockIdx.x * 256 + threadIdx.x;           // over K2_*NCAT_
    if (idx >= K2_ * NCAT_) return;
    int k = idx >> 7, n = idx & 127;
    float v = 0.f;
    if (n < 36)       v = Warg[n * 1024 + k];
    else if (n < 72)  v = Warg[(n - 36) * 1024 + 512 + k];
    else if (n < 106) v = Wev[(n - 72) * 545 + k];
    Wcat[idx] = v;
    if (k == 0) {
        float bv = 0.f;
        if (n >= 36 && n < 72)       bv = barg[n - 36];
        else if (n >= 72 && n < 106) bv = bev[n - 72];
        bias[n] = bv;
    }
}

// ---------------------------------------------------------------------------
// Generic fp32 tiled GEMM: C (MxN) = A (MxK) * Bm (KxN) + bias[n]
// BM=BN=64, BK=16, 256 threads, 4x4 per thread. M, N multiples of 64; K mult of 16.
template <int K>
__global__ __launch_bounds__(256) void k_gemm(const float* __restrict__ A,
                                              const float* __restrict__ Bm,
                                              const float* __restrict__ bias,
                                              float* __restrict__ C, int N) {
    __shared__ float As[16][64];
    __shared__ float Bs[16][64];
    const int tid = threadIdx.x;
    const int m0 = blockIdx.x * 64, n0 = blockIdx.y * 64;
    const int tx = tid & 15, ty = tid >> 4;
    const int a_m = tid >> 2;
    const int a_k = (tid & 3) << 2;
    const int b_k = tid >> 4;
    const int b_n = (tid & 15) << 2;

    float acc[4][4] = {};
    for (int k0 = 0; k0 < K; k0 += 16) {
        float4 av = *(const float4*)&A[(size_t)(m0 + a_m) * K + k0 + a_k];
        float4 bv = *(const float4*)&Bm[(size_t)(k0 + b_k) * N + n0 + b_n];
        __syncthreads();
        As[a_k][a_m] = av.x; As[a_k + 1][a_m] = av.y;
        As[a_k + 2][a_m] = av.z; As[a_k + 3][a_m] = av.w;
        *(float4*)&Bs[b_k][b_n] = bv;
        __syncthreads();
#pragma unroll
        for (int kk = 0; kk < 16; kk++) {
            float4 a4 = *(const float4*)&As[kk][ty << 2];
            float4 b4 = *(const float4*)&Bs[kk][tx << 2];
            float ar[4] = {a4.x, a4.y, a4.z, a4.w};
            float br[4] = {b4.x, b4.y, b4.z, b4.w};
#pragma unroll
            for (int i = 0; i < 4; i++)
#pragma unroll
                for (int j = 0; j < 4; j++) acc[i][j] += ar[i] * br[j];
        }
    }
    float4 bb = *(const float4*)&bias[n0 + (tx << 2)];
#pragma unroll
    for (int i = 0; i < 4; i++) {
        int m = m0 + (ty << 2) + i;
        float4 o;
        o.x = acc[i][0] + bb.x; o.y = acc[i][1] + bb.y;
        o.z = acc[i][2] + bb.z; o.w = acc[i][3] + bb.w;
        *(float4*)&C[(size_t)m * N + n0 + (tx << 2)] = o;
    }
}

// ---------------------------------------------------------------------------
// BiLSTM. One block = one direction x 2 batch rows. 64 blocks, 256 threads.
// Thread t computes gates 4t..4t+3 for both rows, then owns hidden unit t.
// Wt is k-major: Wt[dir][k][g].
__global__ __launch_bounds__(256) void k_lstm(const float* __restrict__ pre,
                                              const float* __restrict__ Wt,
                                              float* __restrict__ hs) {
    const int blk = blockIdx.x;
    const int dir = blk >> 5;
    const int b0 = (blk & 31) << 1;
    const int t = threadIdx.x;
    const float* W = Wt + (size_t)dir * (H_ * 4 * H_);
    __shared__ float sh[2][H_];
    __shared__ float gb[2][4 * H_];
    float c0 = 0.f, c1 = 0.f;
    sh[0][t] = 0.f;
    sh[1][t] = 0.f;
    __syncthreads();
    for (int step = 0; step < L_; step++) {
        const int l = dir ? (L_ - 1 - step) : step;
        const float* p0 = pre + (size_t)(l * B_ + b0) * NPROJ_ + dir * 1024 + (t << 2);
        float4 a0 = *(const float4*)p0;
        float4 a1 = *(const float4*)(p0 + NPROJ_);
#pragma unroll 16
        for (int k = 0; k < H_; k++) {
            float4 w = *(const float4*)(W + (k << 10) + (t << 2));
            float h0 = sh[0][k], h1 = sh[1][k];
            a0.x += w.x * h0; a0.y += w.y * h0; a0.z += w.z * h0; a0.w += w.w * h0;
            a1.x += w.x * h1; a1.y += w.y * h1; a1.z += w.z * h1; a1.w += w.w * h1;
        }
        __syncthreads();
        *(float4*)&gb[0][t << 2] = a0;
        *(float4*)&gb[1][t << 2] = a1;
        __syncthreads();
#pragma unroll
        for (int r = 0; r < 2; r++) {
            float ig = sigmoidf_(gb[r][t]);
            float fg = sigmoidf_(gb[r][H_ + t]);
            float gg = tanhf(gb[r][2 * H_ + t]);
            float og = sigmoidf_(gb[r][3 * H_ + t]);
            float c = r ? c1 : c0;
            c = fg * c + ig * gg;
            if (r) c1 = c; else c0 = c;
            float h = og * tanhf(c);
            sh[r][t] = h;
            hs[(size_t)(l * B_ + b0 + r) * 512 + dir * H_ + t] = h;
        }
        __syncthreads();
    }
}

// ---------------------------------------------------------------------------
// Event head sequential scan. One block (1 wave) per batch row.
// logit_h (incl. b_ev) precomputed in part cols 72..105; only the 33-dim
// g_trg feedback is sequential. Writes event_logits (B, L, NE).
__global__ __launch_bounds__(64) void k_event(const float* __restrict__ part,
                                              const float* __restrict__ Wev,
                                              float* __restrict__ out_ev) {
    const int b = blockIdx.x;
    const int e = threadIdx.x;
    __shared__ float sg[33];
    if (e < 33) sg[e] = 0.f;
    float wreg[33];
    if (e < NE_) {
#pragma unroll
        for (int j = 0; j < 33; j++) wreg[j] = Wev[e * 545 + 512 + j];
    }
    __syncthreads();
    for (int l = 0; l < L_; l++) {
        const int m = l * B_ + b;
        float v = -3.0e38f;
        if (e < NE_) {
            v = part[(size_t)m * NCAT_ + 72 + e];
#pragma unroll
            for (int j = 0; j < 33; j++) v += wreg[j] * sg[j];
            out_ev[((size_t)b * L_ + l) * NE_ + e] = v;
        }
        // wave argmax (first index wins ties, matching jnp.argmax)
        float bv = v;
        int bi = e;
#pragma unroll
        for (int off = 32; off > 0; off >>= 1) {
            float ov = __shfl_xor(bv, off, 64);
            int oi = __shfl_xor(bi, off, 64);
            if (ov > bv || (ov == bv && oi < bi)) { bv = ov; bi = oi; }
        }
        __syncthreads();
        if (bi > 0 && e == bi - 1) sg[e] = 1.f;
        __syncthreads();
    }
}

// ---------------------------------------------------------------------------
// Argument logits broadcast: out[b][i][j][a] = part_i[b][i][a](+b_arg) + part_j[b][j][a]
// One block per (b, i); stages all part_j rows of this b in LDS.
__global__ __launch_bounds__(256) void k_arg(const float* __restrict__ part,
                                             float* __restrict__ out) {
    const int blk = blockIdx.x;            // b*L_ + i
    const int b = blk >> 7, i = blk & 127;
    __shared__ float pj[L_ * NA_];         // 18 KB
    __shared__ float pi_s[NA_];
    const int tid = threadIdx.x;
    if (tid < NA_) pi_s[tid] = part[(size_t)(i * B_ + b) * NCAT_ + 36 + tid];
    for (int idx = tid; idx < L_ * NA_; idx += 256) {
        int j = idx / NA_, a = idx - j * NA_;
        pj[idx] = part[(size_t)(j * B_ + b) * NCAT_ + a];
    }
    __syncthreads();
    float* o = out + (size_t)blk * (L_ * NA_);
    for (int idx = tid; idx < L_ * NA_; idx += 256) {
        int a = idx % NA_;
        o[idx] = pi_s[a] + pj[idx];
    }
}

// ---------------------------------------------------------------------------
extern "C" void kernel_launch(void* const* d_in, const int* in_sizes, int n_in,
                              void* d_out, int out_size, void* d_ws, size_t ws_size,
                              hipStream_t stream) {
    const float* emb  = (const float*)d_in[0];
    const float* Wihf = (const float*)d_in[1];
    const float* Whhf = (const float*)d_in[2];
    const float* bihf = (const float*)d_in[3];
    const float* bhhf = (const float*)d_in[4];
    const float* Wihb = (const float*)d_in[5];
    const float* Whhb = (const float*)d_in[6];
    const float* bihb = (const float*)d_in[7];
    const float* bhhb = (const float*)d_in[8];
    const float* Wev  = (const float*)d_in[9];
    const float* bev  = (const float*)d_in[10];
    const float* Warg = (const float*)d_in[11];
    const float* barg = (const float*)d_in[12];
    const int*   ids  = (const int*)d_in[13];
    float* out = (float*)d_out;
    float* ws  = (float*)d_ws;

    // Workspace layout (floats). X region is reused for `part` (X dead after proj GEMM).
    float* X       = ws;                 // 8192*304   = 2,490,368
    float* part    = ws;                 // 8192*128   = 1,048,576 (reuse of X)
    float* Wt_ih   = ws + 2490368;       // 304*2048   = 622,592
    float* bias_p  = ws + 3112960;       // 2048
    float* Wt_hh   = ws + 3115008;       // 2*256*1024 = 524,288
    float* Wcat    = ws + 3639296;       // 512*128    = 65,536
    float* bias_c  = ws + 3704832;       // 128
    float* pre_all = ws + 3704960;       // 8192*2048  = 16,777,216
    float* hsbuf   = ws + 20482176;      // 8192*512   = 4,194,304
    // total: 24,676,480 floats = 98.7 MB

    k_gather<<<(M_ * KP_) / 256, 256, 0, stream>>>(emb, ids, X);
    k_prep_wih<<<(KP_ * NPROJ_) / 256, 256, 0, stream>>>(Wihf, Wihb, bihf, bhhf, bihb, bhhb, Wt_ih, bias_p);
    k_prep_whh<<<(2 * H_ * 4 * H_) / 256, 256, 0, stream>>>(Whhf, Whhb, Wt_hh);
    k_prep_wcat<<<(K2_ * NCAT_) / 256, 256, 0, stream>>>(Warg, Wev, barg, bev, Wcat, bias_c);

    k_gemm<KP_><<<dim3(M_ / 64, NPROJ_ / 64), 256, 0, stream>>>(X, Wt_ih, bias_p, pre_all, NPROJ_);
    k_lstm<<<64, 256, 0, stream>>>(pre_all, Wt_hh, hsbuf);
    k_gemm<K2_><<<dim3(M_ / 64, NCAT_ / 64), 256, 0, stream>>>(hsbuf, Wcat, bias_c, part, NCAT_);
    k_event<<<B_, 64, 0, stream>>>(part, Wev, out);
    k_arg<<<B_ * L_, 256, 0, stream>>>(part, out + (size_t)B_ * L_ * NE_);
}